// Round 16
// baseline (342.011 us; speedup 1.0000x reference)
//
#include <hip/hip_runtime.h>
#include <hip/hip_bf16.h>
#include <math.h>

#ifndef __has_builtin
#define __has_builtin(x) 0
#endif
#if __has_builtin(__builtin_amdgcn_cvt_pk_fp8_f32) && __has_builtin(__builtin_amdgcn_cvt_pk_f32_fp8)
#define FP8_HW 1
#else
#include <hip/hip_fp8.h>
#endif

#define D 128
#define KVREC 384   // 128 B k (fp8 e4m3) + 256 B v (bf16)

typedef float f32x16 __attribute__((ext_vector_type(16)));
typedef float f32x2  __attribute__((ext_vector_type(2)));
typedef short bf16x8 __attribute__((ext_vector_type(8)));

// gelu tanh-approx, exact rewrite: 0.5x(1+tanh(u)) == x / (1 + e^{-2u})
__device__ __forceinline__ float gelu_fast(float x) {
    float u = 0.7978845608028654f * (x + 0.044715f * x * x * x);
    return x / (1.0f + __expf(-2.0f * u));
}

__device__ __forceinline__ unsigned short f2bf(float f) {
    union { float f; unsigned u; } x; x.f = f;
    unsigned r = x.u + 0x7fff + ((x.u >> 16) & 1);   // RNE
    return (unsigned short)(r >> 16);
}

__device__ __forceinline__ float bflo(unsigned u) { return __uint_as_float(u << 16); }
__device__ __forceinline__ float bfhi(unsigned u) { return __uint_as_float(u & 0xffff0000u); }

__device__ __forceinline__ unsigned char f2fp8(float x) {
#ifdef FP8_HW
    return (unsigned char)(__builtin_amdgcn_cvt_pk_fp8_f32(x, x, 0, false) & 0xFF);
#else
    __hip_fp8_e4m3 h(x); return (unsigned char)h.__x;
#endif
}

__device__ __forceinline__ void fp8x4d(unsigned u, float* f) {
#ifdef FP8_HW
    f32x2 lo = __builtin_amdgcn_cvt_pk_f32_fp8((int)u, false);
    f32x2 hi = __builtin_amdgcn_cvt_pk_f32_fp8((int)u, true);
    f[0] = lo[0]; f[1] = lo[1]; f[2] = hi[0]; f[3] = hi[1];
#else
    #pragma unroll
    for (int i = 0; i < 4; ++i) {
        __hip_fp8_e4m3 h; h.__x = (unsigned char)((u >> (8 * i)) & 0xFF);
        f[i] = (float)h;
    }
#endif
}

// ===== fused_pre: hist+rank (blocks < nbE4, 4 slices) || prepack (last 192) ==

__global__ __launch_bounds__(256) void fused_pre_kernel(
    const int* __restrict__ rows, int* __restrict__ cnt, int* __restrict__ rank,
    int nE, int n, int nbE4,
    const float* __restrict__ W0, const float* __restrict__ W1,
    const float* __restrict__ W2, unsigned short* __restrict__ F)
{
    const int bid = blockIdx.x;
    if (bid < nbE4) {
        // hist: 4 row-slices (halved edge re-read vs 8; atomics still spread)
        const int g  = bid & 3;
        const int lo = (int)(((long long)g * n) >> 2);
        const int hi = (int)(((long long)(g + 1) * n) >> 2);
        const int idx = (bid >> 2) * 1024 + threadIdx.x * 4;
        if (idx + 3 < nE) {
            int4 r4 = *reinterpret_cast<const int4*>(rows + idx);
            int rk[4] = {-1, -1, -1, -1};
            if (r4.x >= lo && r4.x < hi) rk[0] = atomicAdd(&cnt[r4.x], 1);
            if (r4.y >= lo && r4.y < hi) rk[1] = atomicAdd(&cnt[r4.y], 1);
            if (r4.z >= lo && r4.z < hi) rk[2] = atomicAdd(&cnt[r4.z], 1);
            if (r4.w >= lo && r4.w < hi) rk[3] = atomicAdd(&cnt[r4.w], 1);
            #pragma unroll
            for (int j = 0; j < 4; ++j)
                if (rk[j] >= 0) rank[idx + j] = rk[j];
        } else {
            for (int i = 0; i < 4; ++i)
                if (idx + i < nE) {
                    int r = rows[idx + i];
                    if (r >= lo && r < hi) rank[idx + i] = atomicAdd(&cnt[r], 1);
                }
        }
    } else {
        int gidx = (bid - nbE4) * 256 + threadIdx.x;
        if (gidx >= 3 * 32 * 64 * 8) return;
        const int midx = gidx >> 14;
        const int idx  = gidx & 16383;
        const float* W = midx == 0 ? W0 : (midx == 1 ? W1 : W2);
        int j  = idx & 7;
        int l  = (idx >> 3) & 63;
        int kt = (idx >> 9) & 7;
        int ct = idx >> 12;
        int kk = kt * 16 + (l >> 5) * 8 + j;
        int c  = ct * 32 + (l & 31);
        F[gidx] = f2bf(W[kk * D + c]);
    }
}

// ================= scan: block sums, then write (with inline boff re-scan) ===

__global__ __launch_bounds__(256) void scan_bsum_kernel(
    const int* __restrict__ cnt, int* __restrict__ bsum, int n)
{
    __shared__ int s[256];
    const int t = threadIdx.x;
    const int base = blockIdx.x * 1024 + t * 4;
    int sum = 0;
    if (base + 3 < n) {
        int4 c4 = *reinterpret_cast<const int4*>(cnt + base);
        sum = c4.x + c4.y + c4.z + c4.w;
    } else {
        for (int i = 0; i < 4; ++i) if (base + i < n) sum += cnt[base + i];
    }
    s[t] = sum;
    __syncthreads();
    #pragma unroll
    for (int off = 128; off > 0; off >>= 1) {
        if (t < off) s[t] += s[t + off];
        __syncthreads();
    }
    if (t == 0) bsum[blockIdx.x] = s[0];
}

__global__ __launch_bounds__(256) void scan_write2_kernel(
    const int* __restrict__ cnt, const int* __restrict__ bsum, int nb,
    int* __restrict__ rowptr, int n)
{
    __shared__ int s[256];
    const int t = threadIdx.x;

    s[t] = (t < nb) ? bsum[t] : 0;
    __syncthreads();
    #pragma unroll
    for (int off = 1; off < 256; off <<= 1) {
        int v = (t >= off) ? s[t - off] : 0;
        __syncthreads();
        s[t] += v;
        __syncthreads();
    }
    const int boffv = (blockIdx.x > 0) ? s[blockIdx.x - 1] : 0;  // exclusive
    const int total = s[255];
    if (blockIdx.x == 0 && t == 0) rowptr[n] = total;
    __syncthreads();

    const int base = blockIdx.x * 1024 + t * 4;
    int c[4] = {0, 0, 0, 0};
    if (base + 3 < n) {
        int4 c4 = *reinterpret_cast<const int4*>(cnt + base);
        c[0] = c4.x; c[1] = c4.y; c[2] = c4.z; c[3] = c4.w;
    } else {
        for (int i = 0; i < 4; ++i) if (base + i < n) c[i] = cnt[base + i];
    }
    const int tsum = c[0] + c[1] + c[2] + c[3];
    s[t] = tsum;
    __syncthreads();
    #pragma unroll
    for (int off = 1; off < 256; off <<= 1) {
        int v = (t >= off) ? s[t - off] : 0;
        __syncthreads();
        s[t] += v;
        __syncthreads();
    }
    int run = boffv + s[t] - tsum;
    int w0 = run;
    int w1 = run + c[0];
    int w2 = w1 + c[1];
    int w3 = w2 + c[2];
    if (base + 3 < n) {
        *reinterpret_cast<int4*>(rowptr + base) = make_int4(w0, w1, w2, w3);
    } else {
        int w[4] = {w0, w1, w2, w3};
        for (int i = 0; i < 4; ++i) if (base + i < n) rowptr[base + i] = w[i];
    }
}

// ===== fused_mid: scatter || proj_q || proj_kv — low-VGPR envelope ===========
// R16: the R15 tax was VGPR=120 (occ 20.7%). Fixes: (a) NO af[8] preload —
// A-fragments are read per-kt from LDS inside the MFMA loop (LDS BW is free;
// saves 32 VGPR); (b) __launch_bounds__(256,5) pins allocation <= 102 VGPR
// -> 5 waves/SIMD for every block, scatter included. r4 staging stays f32:
// converting at load time would wait on the loads the pipeline is hiding.

__global__ __launch_bounds__(256, 5) void fused_mid_kernel(
    const int* __restrict__ rows, const int* __restrict__ cols,
    const int* __restrict__ rank, const int* __restrict__ rowptr,
    int* __restrict__ colsorted, int nE, int n, int nbSc,
    const float* __restrict__ Xq, const float* __restrict__ Xm,
    const unsigned short* __restrict__ Fq, const float* __restrict__ bq,
    unsigned short* __restrict__ qout,
    const unsigned short* __restrict__ Fk, const float* __restrict__ bk,
    const unsigned short* __restrict__ Fv, const float* __restrict__ bv,
    unsigned char* __restrict__ kv, int m, int nTq, int nTm, int nbP)
{
    __shared__ __align__(16) unsigned short sX[2][32][136];
    const int bid = blockIdx.x;
    const int tid = threadIdx.x;

    if (bid < nbSc) {
        // ---- scatter: rank-based, atomic-free, 4 slices ----
        const int g  = bid & 3;
        const int lo = (int)(((long long)g * n) >> 2);
        const int hi = (int)(((long long)(g + 1) * n) >> 2);
        const int idx = (bid >> 2) * 2048 + tid * 8;
        if (idx + 7 < nE) {
            int4 ra = *reinterpret_cast<const int4*>(rows + idx);
            int4 rb = *reinterpret_cast<const int4*>(rows + idx + 4);
            int4 ca = *reinterpret_cast<const int4*>(cols + idx);
            int4 cb = *reinterpret_cast<const int4*>(cols + idx + 4);
            int4 ka = *reinterpret_cast<const int4*>(rank + idx);
            int4 kb = *reinterpret_cast<const int4*>(rank + idx + 4);
            int r[8] = {ra.x, ra.y, ra.z, ra.w, rb.x, rb.y, rb.z, rb.w};
            int c[8] = {ca.x, ca.y, ca.z, ca.w, cb.x, cb.y, cb.z, cb.w};
            int k[8] = {ka.x, ka.y, ka.z, ka.w, kb.x, kb.y, kb.z, kb.w};
            int p[8];
            #pragma unroll
            for (int j = 0; j < 8; ++j)
                p[j] = (r[j] >= lo && r[j] < hi) ? rowptr[r[j]] + k[j] : -1;
            #pragma unroll
            for (int j = 0; j < 8; ++j)
                if (p[j] >= 0) colsorted[p[j]] = c[j];
        } else {
            for (int i = 0; i < 8; ++i)
                if (idx + i < nE) {
                    int r = rows[idx + i];
                    if (r >= lo && r < hi)
                        colsorted[rowptr[r] + rank[idx + i]] = cols[idx + i];
                }
        }
        return;
    }

    // ---- projections: persistent, double-buffered 32-row tiles ----
    const int pb  = bid - nbSc;
    const bool isQ = pb < nbP;
    const float* X = isQ ? Xq : Xm;
    const int nn   = isQ ? n : m;
    const int nT   = isQ ? nTq : nTm;
    int tile       = isQ ? pb : pb - nbP;
    if (tile >= nT) return;

    const int l = tid & 63;
    const int ct = tid >> 6;           // wave w owns col-tile w
    const int arow = l & 31;
    const int col = ct * 32 + (l & 31);
    const int aoff = (l >> 5) * 8;

    float4 r4[4];
    auto LOAD = [&](int t) {
        const int row0 = t * 32;
        #pragma unroll
        for (int p = 0; p < 4; ++p) {
            int flat = p * 256 + tid;
            int rr = flat >> 5;
            int cc = (flat & 31) * 4;
            int gr = row0 + rr; if (gr >= nn) gr = nn - 1;
            r4[p] = *reinterpret_cast<const float4*>(X + (size_t)gr * D + cc);
        }
    };
    auto STORE_LDS = [&](int buf) {
        #pragma unroll
        for (int p = 0; p < 4; ++p) {
            int flat = p * 256 + tid;
            int rr = flat >> 5;
            int cc = (flat & 31) * 4;
            uint2 pk;
            pk.x = (unsigned)f2bf(r4[p].x) | ((unsigned)f2bf(r4[p].y) << 16);
            pk.y = (unsigned)f2bf(r4[p].z) | ((unsigned)f2bf(r4[p].w) << 16);
            *reinterpret_cast<uint2*>(&sX[buf][rr][cc]) = pk;
        }
    };

    LOAD(tile);
    STORE_LDS(0);
    int cur = 0;
    const float bb1 = isQ ? bq[col] : bk[col];
    const float bb2 = isQ ? 0.0f : bv[col];

    while (tile < nT) {
        const int next = tile + nbP;
        __syncthreads();                       // sX[cur] ready; cross-buffer hazards fenced
        if (next < nT) LOAD(next);             // in flight during compute

        const int row0 = tile * 32;

        if (isQ) {
            f32x16 acc = {};
            #pragma unroll
            for (int kt = 0; kt < 8; ++kt) {
                bf16x8 afkt = *reinterpret_cast<const bf16x8*>(&sX[cur][arow][kt * 16 + aoff]);
                bf16x8 bfr = *reinterpret_cast<const bf16x8*>(Fq + ((size_t)((ct * 8 + kt) * 64 + l) * 8));
                acc = __builtin_amdgcn_mfma_f32_32x32x16_bf16(afkt, bfr, acc, 0, 0, 0);
            }
            #pragma unroll
            for (int reg = 0; reg < 16; ++reg) {
                int rr = (reg & 3) + 8 * (reg >> 2) + 4 * (l >> 5);
                int gr = row0 + rr;
                if (gr < nn)
                    qout[(size_t)gr * D + col] = f2bf(gelu_fast(acc[reg] + bb1));
            }
        } else {
            #pragma unroll 1
            for (int mat = 0; mat < 2; ++mat) {
                const unsigned short* F = mat ? Fv : Fk;
                const float bb          = mat ? bb2 : bb1;
                f32x16 acc = {};
                #pragma unroll
                for (int kt = 0; kt < 8; ++kt) {
                    bf16x8 afkt = *reinterpret_cast<const bf16x8*>(&sX[cur][arow][kt * 16 + aoff]);
                    bf16x8 bfr = *reinterpret_cast<const bf16x8*>(F + ((size_t)((ct * 8 + kt) * 64 + l) * 8));
                    acc = __builtin_amdgcn_mfma_f32_32x32x16_bf16(afkt, bfr, acc, 0, 0, 0);
                }
                #pragma unroll
                for (int reg = 0; reg < 16; ++reg) {
                    int rr = (reg & 3) + 8 * (reg >> 2) + 4 * (l >> 5);
                    int gr = row0 + rr;
                    if (gr < nn) {
                        unsigned char* rec = kv + (size_t)gr * KVREC;
                        float val = gelu_fast(acc[reg] + bb);
                        if (mat == 0)
                            rec[col] = f2fp8(val);
                        else
                            reinterpret_cast<unsigned short*>(rec + 128)[col] = f2bf(val);
                    }
                }
            }
        }

        if (next < nT) STORE_LDS(cur ^ 1);     // waits on LOAD(next) only here
        cur ^= 1;
        tile = next;
    }
}

// ===== aggregation: one wave/row, 4 edge slots x 16 dim lanes ================
// colsorted prefetched 2 iterations ahead; only kv gather latency exposed.
__global__ __launch_bounds__(256) void agg_kernel(
    const unsigned short* __restrict__ q, const unsigned char* __restrict__ kv,
    const int* __restrict__ rowptr, const int* __restrict__ colsorted,
    float* __restrict__ out, int n)
{
    const int wave = (blockIdx.x * 256 + threadIdx.x) >> 6;
    if (wave >= n) return;
    const int lane = threadIdx.x & 63;
    const int sub  = lane >> 4;
    const int l    = lane & 15;

    const uint4 qa = *reinterpret_cast<const uint4*>(q + (size_t)wave * D + l * 8);
    float qf[8];
    qf[0] = bflo(qa.x); qf[1] = bfhi(qa.x);
    qf[2] = bflo(qa.y); qf[3] = bfhi(qa.y);
    qf[4] = bflo(qa.z); qf[5] = bfhi(qa.z);
    qf[6] = bflo(qa.w); qf[7] = bfhi(qa.w);

    float acc[8] = {0.f,0.f,0.f,0.f,0.f,0.f,0.f,0.f};
    const int start = rowptr[wave], end = rowptr[wave + 1];

    int i  = start + sub;
    int cA = (i     < end) ? colsorted[i]     : 0;
    int cB = (i + 4 < end) ? colsorted[i + 4] : 0;

    #pragma unroll 2
    for (; i < end; i += 4) {
        const int c = cA;
        cA = cB;
        cB = (i + 8 < end) ? colsorted[i + 8] : 0;

        const unsigned char* rec = kv + (size_t)c * KVREC;
        const uint2 kb = *reinterpret_cast<const uint2*>(rec + l * 8);
        const uint4 vb = *reinterpret_cast<const uint4*>(rec + 128 + l * 16);

        float kf[8];
        fp8x4d(kb.x, kf); fp8x4d(kb.y, kf + 4);

        float dot = 0.0f;
        #pragma unroll
        for (int j = 0; j < 8; ++j) dot = fmaf(qf[j], kf[j], dot);
        dot += __shfl_xor(dot, 1);
        dot += __shfl_xor(dot, 2);
        dot += __shfl_xor(dot, 4);
        dot += __shfl_xor(dot, 8);
        const float coef = 1.0f / (1.0f + __expf(-dot * 0.08838834764831845f));

        acc[0] = fmaf(coef, bflo(vb.x), acc[0]);
        acc[1] = fmaf(coef, bfhi(vb.x), acc[1]);
        acc[2] = fmaf(coef, bflo(vb.y), acc[2]);
        acc[3] = fmaf(coef, bfhi(vb.y), acc[3]);
        acc[4] = fmaf(coef, bflo(vb.z), acc[4]);
        acc[5] = fmaf(coef, bfhi(vb.z), acc[5]);
        acc[6] = fmaf(coef, bflo(vb.w), acc[6]);
        acc[7] = fmaf(coef, bfhi(vb.w), acc[7]);
    }

    #pragma unroll
    for (int j = 0; j < 8; ++j) {
        acc[j] += __shfl_xor(acc[j], 16);
        acc[j] += __shfl_xor(acc[j], 32);
    }

    if (sub == 0) {
        float* op = out + (size_t)wave * D + l * 8;
        float4 o0 = {acc[0], acc[1], acc[2], acc[3]};
        float4 o1 = {acc[4], acc[5], acc[6], acc[7]};
        *reinterpret_cast<float4*>(op)     = o0;
        *reinterpret_cast<float4*>(op + 4) = o1;
    }
}

extern "C" void kernel_launch(void* const* d_in, const int* in_sizes, int n_in,
                              void* d_out, int out_size, void* d_ws, size_t ws_size,
                              hipStream_t stream) {
    const float* query  = (const float*)d_in[0];
    const float* memory = (const float*)d_in[1];
    const float* Wq     = (const float*)d_in[2];
    const float* bq     = (const float*)d_in[3];
    const float* Wk     = (const float*)d_in[4];
    const float* bk     = (const float*)d_in[5];
    const float* Wv     = (const float*)d_in[6];
    const float* bv     = (const float*)d_in[7];
    const int*   erows  = (const int*)d_in[8];
    const int*   ecols  = (const int*)d_in[9];

    const int n  = in_sizes[0] / D;   // 100000
    const int m  = in_sizes[1] / D;   // 100000
    const int nE = in_sizes[8];       // 1600000

    char* base = (char*)d_ws;
    size_t off = 0;
    auto carve = [&](size_t bytes) -> char* {
        char* p = base + off;
        off = (off + bytes + 255) & ~(size_t)255;
        return p;
    };
    unsigned short* q   = (unsigned short*)carve((size_t)n * D * sizeof(unsigned short));
    unsigned char*  kv  = (unsigned char*) carve((size_t)m * KVREC);
    unsigned short* F   = (unsigned short*)carve(3 * 32 * 64 * 8 * sizeof(unsigned short));
    int*   rowptr    = (int*)carve((size_t)(n + 1) * sizeof(int));
    int*   cnt       = (int*)carve((size_t)(n + 1) * sizeof(int));
    int*   rank      = (int*)carve((size_t)nE * sizeof(int));
    int*   bsum      = (int*)carve(256 * sizeof(int));
    int*   colsorted = (int*)carve((size_t)nE * sizeof(int));
    float* out       = (float*)d_out;

    unsigned short* Fq = F;
    unsigned short* Fk = F + 16384;
    unsigned short* Fv = F + 32768;

    dim3 blk(256);
    const int nbScan = (n + 1023) / 1024;            // 98 <= 256
    const int nbE4   = ((nE + 1023) / 1024) * 4;     // hist blocks (4 edges/thr, 4 slices)
    const int nbSc   = ((nE + 2047) / 2048) * 4;     // scatter blocks (8 edges/thr, 4 slices)
    const int nTq    = (n + 31) / 32;                // 32-row proj tiles
    const int nTm    = (m + 31) / 32;
    const int nbP    = 1024;                         // persistent proj blocks per matrix

    // 1) zero counters
    hipMemsetAsync(cnt, 0, (size_t)(n + 1) * sizeof(int), stream);
    // 2) hist(+rank) || prepack
    fused_pre_kernel<<<dim3(nbE4 + 192), blk, 0, stream>>>(
        erows, cnt, rank, nE, n, nbE4, Wq, Wk, Wv, F);
    // 3) block sums
    scan_bsum_kernel<<<dim3(nbScan), blk, 0, stream>>>(cnt, bsum, n);
    // 4) rowptr (inline boff re-scan)
    scan_write2_kernel<<<dim3(nbScan), blk, 0, stream>>>(cnt, bsum, nbScan, rowptr, n);
    // 5) scatter || proj_q || proj_kv (one dispatch; low-VGPR envelope)
    fused_mid_kernel<<<dim3(nbSc + 2 * nbP), blk, 0, stream>>>(
        erows, ecols, rank, rowptr, colsorted, nE, n, nbSc,
        query, memory, Fq, bq, q, Fk, bk, Fv, bv, kv, m, nTq, nTm, nbP);
    // 6) aggregation (writes all outputs; no out memset needed)
    agg_kernel<<<dim3((n * 64 + 255) / 256), blk, 0, stream>>>(q, kv, rowptr, colsorted, out, n);
}

// Round 17
// 250.870 us; speedup vs baseline: 1.3633x; 1.3633x over previous
//
#include <hip/hip_runtime.h>
#include <hip/hip_bf16.h>
#include <math.h>

#ifndef __has_builtin
#define __has_builtin(x) 0
#endif
#if __has_builtin(__builtin_amdgcn_cvt_pk_fp8_f32) && __has_builtin(__builtin_amdgcn_cvt_pk_f32_fp8)
#define FP8_HW 1
#else
#include <hip/hip_fp8.h>
#endif

#define D 128
#define KVREC 384   // 128 B k (fp8 e4m3) + 256 B v (bf16)

typedef float f32x4  __attribute__((ext_vector_type(4)));
typedef float f32x2  __attribute__((ext_vector_type(2)));
typedef short bf16x8 __attribute__((ext_vector_type(8)));

// gelu tanh-approx, exact rewrite: 0.5x(1+tanh(u)) == x / (1 + e^{-2u})
__device__ __forceinline__ float gelu_fast(float x) {
    float u = 0.7978845608028654f * (x + 0.044715f * x * x * x);
    return x / (1.0f + __expf(-2.0f * u));
}

__device__ __forceinline__ unsigned short f2bf(float f) {
    union { float f; unsigned u; } x; x.f = f;
    unsigned r = x.u + 0x7fff + ((x.u >> 16) & 1);   // RNE
    return (unsigned short)(r >> 16);
}

__device__ __forceinline__ float bflo(unsigned u) { return __uint_as_float(u << 16); }
__device__ __forceinline__ float bfhi(unsigned u) { return __uint_as_float(u & 0xffff0000u); }

__device__ __forceinline__ unsigned char f2fp8(float x) {
#ifdef FP8_HW
    return (unsigned char)(__builtin_amdgcn_cvt_pk_fp8_f32(x, x, 0, false) & 0xFF);
#else
    __hip_fp8_e4m3 h(x); return (unsigned char)h.__x;
#endif
}

__device__ __forceinline__ void fp8x4d(unsigned u, float* f) {
#ifdef FP8_HW
    f32x2 lo = __builtin_amdgcn_cvt_pk_f32_fp8((int)u, false);
    f32x2 hi = __builtin_amdgcn_cvt_pk_f32_fp8((int)u, true);
    f[0] = lo[0]; f[1] = lo[1]; f[2] = hi[0]; f[3] = hi[1];
#else
    #pragma unroll
    for (int i = 0; i < 4; ++i) {
        __hip_fp8_e4m3 h; h.__x = (unsigned char)((u >> (8 * i)) & 0xFF);
        f[i] = (float)h;
    }
#endif
}

// ===== fused_pre: hist+rank (blocks < nbE8, 8 slices) || prepack (last 192) ==
// R17: 16x16x32 B-fragment order:
// F[((ct*4+kc)*64+l)*8+j] = bf16(W[(kc*32+(l>>4)*8+j)*128 + ct*16+(l&15)])

__global__ __launch_bounds__(256) void fused_pre_kernel(
    const int* __restrict__ rows, int* __restrict__ cnt, int* __restrict__ rank,
    int nE, int n, int nbE8,
    const float* __restrict__ W0, const float* __restrict__ W1,
    const float* __restrict__ W2, unsigned short* __restrict__ F)
{
    const int bid = blockIdx.x;
    if (bid < nbE8) {
        const int g  = bid & 7;
        const int lo = (int)(((long long)g * n) >> 3);
        const int hi = (int)(((long long)(g + 1) * n) >> 3);
        const int idx = (bid >> 3) * 1024 + threadIdx.x * 4;
        if (idx + 3 < nE) {
            int4 r4 = *reinterpret_cast<const int4*>(rows + idx);
            int rk[4] = {-1, -1, -1, -1};
            if (r4.x >= lo && r4.x < hi) rk[0] = atomicAdd(&cnt[r4.x], 1);
            if (r4.y >= lo && r4.y < hi) rk[1] = atomicAdd(&cnt[r4.y], 1);
            if (r4.z >= lo && r4.z < hi) rk[2] = atomicAdd(&cnt[r4.z], 1);
            if (r4.w >= lo && r4.w < hi) rk[3] = atomicAdd(&cnt[r4.w], 1);
            #pragma unroll
            for (int j = 0; j < 4; ++j)
                if (rk[j] >= 0) rank[idx + j] = rk[j];
        } else {
            for (int i = 0; i < 4; ++i)
                if (idx + i < nE) {
                    int r = rows[idx + i];
                    if (r >= lo && r < hi) rank[idx + i] = atomicAdd(&cnt[r], 1);
                }
        }
    } else {
        int gidx = (bid - nbE8) * 256 + threadIdx.x;
        if (gidx >= 3 * 32 * 64 * 8) return;
        const int midx = gidx >> 14;
        const int idx  = gidx & 16383;
        const float* W = midx == 0 ? W0 : (midx == 1 ? W1 : W2);
        int j  = idx & 7;
        int l  = (idx >> 3) & 63;
        int kc = (idx >> 9) & 3;
        int ct = idx >> 11;                        // 0..7
        int kk = kc * 32 + (l >> 4) * 8 + j;
        int c  = ct * 16 + (l & 15);
        F[gidx] = f2bf(W[kk * D + c]);
    }
}

// ================= scan: block sums, then write (with inline boff re-scan) ===

__global__ __launch_bounds__(256) void scan_bsum_kernel(
    const int* __restrict__ cnt, int* __restrict__ bsum, int n)
{
    __shared__ int s[256];
    const int t = threadIdx.x;
    const int base = blockIdx.x * 1024 + t * 4;
    int sum = 0;
    if (base + 3 < n) {
        int4 c4 = *reinterpret_cast<const int4*>(cnt + base);
        sum = c4.x + c4.y + c4.z + c4.w;
    } else {
        for (int i = 0; i < 4; ++i) if (base + i < n) sum += cnt[base + i];
    }
    s[t] = sum;
    __syncthreads();
    #pragma unroll
    for (int off = 128; off > 0; off >>= 1) {
        if (t < off) s[t] += s[t + off];
        __syncthreads();
    }
    if (t == 0) bsum[blockIdx.x] = s[0];
}

__global__ __launch_bounds__(256) void scan_write2_kernel(
    const int* __restrict__ cnt, const int* __restrict__ bsum, int nb,
    int* __restrict__ rowptr, int n)
{
    __shared__ int s[256];
    const int t = threadIdx.x;

    s[t] = (t < nb) ? bsum[t] : 0;
    __syncthreads();
    #pragma unroll
    for (int off = 1; off < 256; off <<= 1) {
        int v = (t >= off) ? s[t - off] : 0;
        __syncthreads();
        s[t] += v;
        __syncthreads();
    }
    const int boffv = (blockIdx.x > 0) ? s[blockIdx.x - 1] : 0;  // exclusive
    const int total = s[255];
    if (blockIdx.x == 0 && t == 0) rowptr[n] = total;
    __syncthreads();

    const int base = blockIdx.x * 1024 + t * 4;
    int c[4] = {0, 0, 0, 0};
    if (base + 3 < n) {
        int4 c4 = *reinterpret_cast<const int4*>(cnt + base);
        c[0] = c4.x; c[1] = c4.y; c[2] = c4.z; c[3] = c4.w;
    } else {
        for (int i = 0; i < 4; ++i) if (base + i < n) c[i] = cnt[base + i];
    }
    const int tsum = c[0] + c[1] + c[2] + c[3];
    s[t] = tsum;
    __syncthreads();
    #pragma unroll
    for (int off = 1; off < 256; off <<= 1) {
        int v = (t >= off) ? s[t - off] : 0;
        __syncthreads();
        s[t] += v;
        __syncthreads();
    }
    int run = boffv + s[t] - tsum;
    int w0 = run;
    int w1 = run + c[0];
    int w2 = w1 + c[1];
    int w3 = w2 + c[2];
    if (base + 3 < n) {
        *reinterpret_cast<int4*>(rowptr + base) = make_int4(w0, w1, w2, w3);
    } else {
        int w[4] = {w0, w1, w2, w3};
        for (int i = 0; i < 4; ++i) if (base + i < n) rowptr[base + i] = w[i];
    }
}

// ===== fused_mid: scatter || proj_q || proj_kv — 16x16x32 MFMA (low VGPR) ====
// R17: R15's tax was VGPR=120 (16-reg 32x32 acc + af[8] preload -> 4 waves/
// SIMD for all blocks incl. scatter). Structural fix: 16x16x32 MFMA (4-reg
// acc) + inline per-MFMA A reads from LDS. NO launch_bounds pin (R16 lesson:
// pinning below natural allocation = scratch spills, WRITE_SIZE 95->354 MB).

__global__ __launch_bounds__(256) void fused_mid_kernel(
    const int* __restrict__ rows, const int* __restrict__ cols,
    const int* __restrict__ rank, const int* __restrict__ rowptr,
    int* __restrict__ colsorted, int nE, int n, int nbSc,
    const float* __restrict__ Xq, const float* __restrict__ Xm,
    const unsigned short* __restrict__ Fq, const float* __restrict__ bq,
    unsigned short* __restrict__ qout,
    const unsigned short* __restrict__ Fk, const float* __restrict__ bk,
    const unsigned short* __restrict__ Fv, const float* __restrict__ bv,
    unsigned char* __restrict__ kv, int m, int nTq, int nTm, int nbP)
{
    __shared__ __align__(16) unsigned short sX[2][32][136];
    const int bid = blockIdx.x;
    const int tid = threadIdx.x;

    if (bid < nbSc) {
        // ---- scatter: rank-based, atomic-free, 4 slices ----
        const int g  = bid & 3;
        const int lo = (int)(((long long)g * n) >> 2);
        const int hi = (int)(((long long)(g + 1) * n) >> 2);
        const int idx = (bid >> 2) * 2048 + tid * 8;
        if (idx + 7 < nE) {
            int4 ra = *reinterpret_cast<const int4*>(rows + idx);
            int4 rb = *reinterpret_cast<const int4*>(rows + idx + 4);
            int4 ca = *reinterpret_cast<const int4*>(cols + idx);
            int4 cb = *reinterpret_cast<const int4*>(cols + idx + 4);
            int4 ka = *reinterpret_cast<const int4*>(rank + idx);
            int4 kb = *reinterpret_cast<const int4*>(rank + idx + 4);
            int r[8] = {ra.x, ra.y, ra.z, ra.w, rb.x, rb.y, rb.z, rb.w};
            int c[8] = {ca.x, ca.y, ca.z, ca.w, cb.x, cb.y, cb.z, cb.w};
            int k[8] = {ka.x, ka.y, ka.z, ka.w, kb.x, kb.y, kb.z, kb.w};
            int p[8];
            #pragma unroll
            for (int j = 0; j < 8; ++j)
                p[j] = (r[j] >= lo && r[j] < hi) ? rowptr[r[j]] + k[j] : -1;
            #pragma unroll
            for (int j = 0; j < 8; ++j)
                if (p[j] >= 0) colsorted[p[j]] = c[j];
        } else {
            for (int i = 0; i < 8; ++i)
                if (idx + i < nE) {
                    int r = rows[idx + i];
                    if (r >= lo && r < hi)
                        colsorted[rowptr[r] + rank[idx + i]] = cols[idx + i];
                }
        }
        return;
    }

    // ---- projections: persistent, double-buffered 32-row tiles ----
    const int pb  = bid - nbSc;
    const bool isQ = pb < nbP;
    const float* X = isQ ? Xq : Xm;
    const int nn   = isQ ? n : m;
    const int nT   = isQ ? nTq : nTm;
    int tile       = isQ ? pb : pb - nbP;
    if (tile >= nT) return;

    const int l = tid & 63;
    const int w = tid >> 6;            // wave w owns col-tiles w*2, w*2+1
    const int lr = l & 15;             // A row within 16-row tile; also C col
    const int lg = l >> 4;             // k-group (A/B) and row-group (C/D)
    const int col0 = (w * 2)     * 16 + lr;
    const int col1 = (w * 2 + 1) * 16 + lr;

    float4 r4[4];
    auto LOAD = [&](int t) {
        const int row0 = t * 32;
        #pragma unroll
        for (int p = 0; p < 4; ++p) {
            int flat = p * 256 + tid;
            int rr = flat >> 5;
            int cc = (flat & 31) * 4;
            int gr = row0 + rr; if (gr >= nn) gr = nn - 1;
            r4[p] = *reinterpret_cast<const float4*>(X + (size_t)gr * D + cc);
        }
    };
    auto STORE_LDS = [&](int buf) {
        #pragma unroll
        for (int p = 0; p < 4; ++p) {
            int flat = p * 256 + tid;
            int rr = flat >> 5;
            int cc = (flat & 31) * 4;
            uint2 pk;
            pk.x = (unsigned)f2bf(r4[p].x) | ((unsigned)f2bf(r4[p].y) << 16);
            pk.y = (unsigned)f2bf(r4[p].z) | ((unsigned)f2bf(r4[p].w) << 16);
            *reinterpret_cast<uint2*>(&sX[buf][rr][cc]) = pk;
        }
    };

    LOAD(tile);
    STORE_LDS(0);
    int cur = 0;

    const float bq0 = isQ ? bq[col0] : bk[col0];
    const float bq1 = isQ ? bq[col1] : bk[col1];
    const float bv0 = isQ ? 0.0f : bv[col0];
    const float bv1 = isQ ? 0.0f : bv[col1];

    while (tile < nT) {
        const int next = tile + nbP;
        __syncthreads();                       // sX[cur] ready; cross-buffer hazards fenced
        if (next < nT) LOAD(next);             // in flight during compute

        const int row0 = tile * 32;

        #pragma unroll 1
        for (int rt = 0; rt < 2; ++rt) {       // 16-row sub-tiles
            const int rbase = row0 + rt * 16 + lg * 4;
            if (isQ) {
                #pragma unroll 1
                for (int ci = 0; ci < 2; ++ci) {
                    const int ct = w * 2 + ci;
                    f32x4 acc = {};
                    #pragma unroll
                    for (int kc = 0; kc < 4; ++kc) {
                        bf16x8 af = *reinterpret_cast<const bf16x8*>(
                            &sX[cur][rt * 16 + lr][kc * 32 + lg * 8]);
                        bf16x8 bf = *reinterpret_cast<const bf16x8*>(
                            Fq + ((size_t)((ct * 4 + kc) * 64 + l) * 8));
                        acc = __builtin_amdgcn_mfma_f32_16x16x32_bf16(af, bf, acc, 0, 0, 0);
                    }
                    const int col = ci ? col1 : col0;
                    const float bb = ci ? bq1 : bq0;
                    #pragma unroll
                    for (int reg = 0; reg < 4; ++reg) {
                        int gr = rbase + reg;
                        if (gr < nn)
                            qout[(size_t)gr * D + col] = f2bf(gelu_fast(acc[reg] + bb));
                    }
                }
            } else {
                #pragma unroll 1
                for (int mat = 0; mat < 2; ++mat) {
                    const unsigned short* F = mat ? Fv : Fk;
                    #pragma unroll 1
                    for (int ci = 0; ci < 2; ++ci) {
                        const int ct = w * 2 + ci;
                        f32x4 acc = {};
                        #pragma unroll
                        for (int kc = 0; kc < 4; ++kc) {
                            bf16x8 af = *reinterpret_cast<const bf16x8*>(
                                &sX[cur][rt * 16 + lr][kc * 32 + lg * 8]);
                            bf16x8 bf = *reinterpret_cast<const bf16x8*>(
                                F + ((size_t)((ct * 4 + kc) * 64 + l) * 8));
                            acc = __builtin_amdgcn_mfma_f32_16x16x32_bf16(af, bf, acc, 0, 0, 0);
                        }
                        const int col = ci ? col1 : col0;
                        const float bb = mat ? (ci ? bv1 : bv0) : (ci ? bq1 : bq0);
                        #pragma unroll
                        for (int reg = 0; reg < 4; ++reg) {
                            int gr = rbase + reg;
                            if (gr < nn) {
                                unsigned char* rec = kv + (size_t)gr * KVREC;
                                float val = gelu_fast(acc[reg] + bb);
                                if (mat == 0)
                                    rec[col] = f2fp8(val);
                                else
                                    reinterpret_cast<unsigned short*>(rec + 128)[col] = f2bf(val);
                            }
                        }
                    }
                }
            }
        }

        if (next < nT) STORE_LDS(cur ^ 1);     // waits on LOAD(next) only here
        cur ^= 1;
        tile = next;
    }
}

// ===== aggregation: one wave/row, 4 edge slots x 16 dim lanes ================
// colsorted prefetched 2 iterations ahead; only kv gather latency exposed.
__global__ __launch_bounds__(256) void agg_kernel(
    const unsigned short* __restrict__ q, const unsigned char* __restrict__ kv,
    const int* __restrict__ rowptr, const int* __restrict__ colsorted,
    float* __restrict__ out, int n)
{
    const int wave = (blockIdx.x * 256 + threadIdx.x) >> 6;
    if (wave >= n) return;
    const int lane = threadIdx.x & 63;
    const int sub  = lane >> 4;
    const int l    = lane & 15;

    const uint4 qa = *reinterpret_cast<const uint4*>(q + (size_t)wave * D + l * 8);
    float qf[8];
    qf[0] = bflo(qa.x); qf[1] = bfhi(qa.x);
    qf[2] = bflo(qa.y); qf[3] = bfhi(qa.y);
    qf[4] = bflo(qa.z); qf[5] = bfhi(qa.z);
    qf[6] = bflo(qa.w); qf[7] = bfhi(qa.w);

    float acc[8] = {0.f,0.f,0.f,0.f,0.f,0.f,0.f,0.f};
    const int start = rowptr[wave], end = rowptr[wave + 1];

    int i  = start + sub;
    int cA = (i     < end) ? colsorted[i]     : 0;
    int cB = (i + 4 < end) ? colsorted[i + 4] : 0;

    #pragma unroll 2
    for (; i < end; i += 4) {
        const int c = cA;
        cA = cB;
        cB = (i + 8 < end) ? colsorted[i + 8] : 0;

        const unsigned char* rec = kv + (size_t)c * KVREC;
        const uint2 kb = *reinterpret_cast<const uint2*>(rec + l * 8);
        const uint4 vb = *reinterpret_cast<const uint4*>(rec + 128 + l * 16);

        float kf[8];
        fp8x4d(kb.x, kf); fp8x4d(kb.y, kf + 4);

        float dot = 0.0f;
        #pragma unroll
        for (int j = 0; j < 8; ++j) dot = fmaf(qf[j], kf[j], dot);
        dot += __shfl_xor(dot, 1);
        dot += __shfl_xor(dot, 2);
        dot += __shfl_xor(dot, 4);
        dot += __shfl_xor(dot, 8);
        const float coef = 1.0f / (1.0f + __expf(-dot * 0.08838834764831845f));

        acc[0] = fmaf(coef, bflo(vb.x), acc[0]);
        acc[1] = fmaf(coef, bfhi(vb.x), acc[1]);
        acc[2] = fmaf(coef, bflo(vb.y), acc[2]);
        acc[3] = fmaf(coef, bfhi(vb.y), acc[3]);
        acc[4] = fmaf(coef, bflo(vb.z), acc[4]);
        acc[5] = fmaf(coef, bfhi(vb.z), acc[5]);
        acc[6] = fmaf(coef, bflo(vb.w), acc[6]);
        acc[7] = fmaf(coef, bfhi(vb.w), acc[7]);
    }

    #pragma unroll
    for (int j = 0; j < 8; ++j) {
        acc[j] += __shfl_xor(acc[j], 16);
        acc[j] += __shfl_xor(acc[j], 32);
    }

    if (sub == 0) {
        float* op = out + (size_t)wave * D + l * 8;
        float4 o0 = {acc[0], acc[1], acc[2], acc[3]};
        float4 o1 = {acc[4], acc[5], acc[6], acc[7]};
        *reinterpret_cast<float4*>(op)     = o0;
        *reinterpret_cast<float4*>(op + 4) = o1;
    }
}

extern "C" void kernel_launch(void* const* d_in, const int* in_sizes, int n_in,
                              void* d_out, int out_size, void* d_ws, size_t ws_size,
                              hipStream_t stream) {
    const float* query  = (const float*)d_in[0];
    const float* memory = (const float*)d_in[1];
    const float* Wq     = (const float*)d_in[2];
    const float* bq     = (const float*)d_in[3];
    const float* Wk     = (const float*)d_in[4];
    const float* bk     = (const float*)d_in[5];
    const float* Wv     = (const float*)d_in[6];
    const float* bv     = (const float*)d_in[7];
    const int*   erows  = (const int*)d_in[8];
    const int*   ecols  = (const int*)d_in[9];

    const int n  = in_sizes[0] / D;   // 100000
    const int m  = in_sizes[1] / D;   // 100000
    const int nE = in_sizes[8];       // 1600000

    char* base = (char*)d_ws;
    size_t off = 0;
    auto carve = [&](size_t bytes) -> char* {
        char* p = base + off;
        off = (off + bytes + 255) & ~(size_t)255;
        return p;
    };
    unsigned short* q   = (unsigned short*)carve((size_t)n * D * sizeof(unsigned short));
    unsigned char*  kv  = (unsigned char*) carve((size_t)m * KVREC);
    unsigned short* F   = (unsigned short*)carve(3 * 32 * 64 * 8 * sizeof(unsigned short));
    int*   rowptr    = (int*)carve((size_t)(n + 1) * sizeof(int));
    int*   cnt       = (int*)carve((size_t)(n + 1) * sizeof(int));
    int*   rank      = (int*)carve((size_t)nE * sizeof(int));
    int*   bsum      = (int*)carve(256 * sizeof(int));
    int*   colsorted = (int*)carve((size_t)nE * sizeof(int));
    float* out       = (float*)d_out;

    unsigned short* Fq = F;
    unsigned short* Fk = F + 16384;
    unsigned short* Fv = F + 32768;

    dim3 blk(256);
    const int nbScan = (n + 1023) / 1024;            // 98 <= 256
    const int nbE8   = ((nE + 1023) / 1024) * 8;     // hist blocks (4 edges/thr, 8 slices)
    const int nbSc   = ((nE + 2047) / 2048) * 4;     // scatter blocks (8 edges/thr, 4 slices)
    const int nTq    = (n + 31) / 32;                // 32-row proj tiles
    const int nTm    = (m + 31) / 32;
    const int nbP    = 1024;                         // persistent proj blocks per matrix

    // 1) zero counters
    hipMemsetAsync(cnt, 0, (size_t)(n + 1) * sizeof(int), stream);
    // 2) hist(+rank) || prepack (16x16x32 fragment order)
    fused_pre_kernel<<<dim3(nbE8 + 192), blk, 0, stream>>>(
        erows, cnt, rank, nE, n, nbE8, Wq, Wk, Wv, F);
    // 3) block sums
    scan_bsum_kernel<<<dim3(nbScan), blk, 0, stream>>>(cnt, bsum, n);
    // 4) rowptr (inline boff re-scan)
    scan_write2_kernel<<<dim3(nbScan), blk, 0, stream>>>(cnt, bsum, nbScan, rowptr, n);
    // 5) scatter || proj_q || proj_kv (16x16 MFMA, natural VGPR allocation)
    fused_mid_kernel<<<dim3(nbSc + 2 * nbP), blk, 0, stream>>>(
        erows, ecols, rank, rowptr, colsorted, nE, n, nbSc,
        query, memory, Fq, bq, q, Fk, bk, Fv, bv, kv, m, nTq, nTm, nbP);
    // 6) aggregation (writes all outputs; no out memset needed)
    agg_kernel<<<dim3((n * 64 + 255) / 256), blk, 0, stream>>>(q, kv, rowptr, colsorted, out, n);
}

// Round 18
// 249.367 us; speedup vs baseline: 1.3715x; 1.0060x over previous
//
#include <hip/hip_runtime.h>
#include <hip/hip_bf16.h>
#include <math.h>

#ifndef __has_builtin
#define __has_builtin(x) 0
#endif
#if __has_builtin(__builtin_amdgcn_cvt_pk_fp8_f32) && __has_builtin(__builtin_amdgcn_cvt_pk_f32_fp8)
#define FP8_HW 1
#else
#include <hip/hip_fp8.h>
#endif

#define D 128
#define KVREC 384   // 128 B k (fp8 e4m3) + 256 B v (bf16)

typedef float f32x4  __attribute__((ext_vector_type(4)));
typedef float f32x2  __attribute__((ext_vector_type(2)));
typedef short bf16x8 __attribute__((ext_vector_type(8)));

// gelu tanh-approx, exact rewrite: 0.5x(1+tanh(u)) == x / (1 + e^{-2u})
__device__ __forceinline__ float gelu_fast(float x) {
    float u = 0.7978845608028654f * (x + 0.044715f * x * x * x);
    return x / (1.0f + __expf(-2.0f * u));
}

__device__ __forceinline__ unsigned short f2bf(float f) {
    union { float f; unsigned u; } x; x.f = f;
    unsigned r = x.u + 0x7fff + ((x.u >> 16) & 1);   // RNE
    return (unsigned short)(r >> 16);
}

__device__ __forceinline__ float bflo(unsigned u) { return __uint_as_float(u << 16); }
__device__ __forceinline__ float bfhi(unsigned u) { return __uint_as_float(u & 0xffff0000u); }

__device__ __forceinline__ unsigned char f2fp8(float x) {
#ifdef FP8_HW
    return (unsigned char)(__builtin_amdgcn_cvt_pk_fp8_f32(x, x, 0, false) & 0xFF);
#else
    __hip_fp8_e4m3 h(x); return (unsigned char)h.__x;
#endif
}

__device__ __forceinline__ void fp8x4d(unsigned u, float* f) {
#ifdef FP8_HW
    f32x2 lo = __builtin_amdgcn_cvt_pk_f32_fp8((int)u, false);
    f32x2 hi = __builtin_amdgcn_cvt_pk_f32_fp8((int)u, true);
    f[0] = lo[0]; f[1] = lo[1]; f[2] = hi[0]; f[3] = hi[1];
#else
    #pragma unroll
    for (int i = 0; i < 4; ++i) {
        __hip_fp8_e4m3 h; h.__x = (unsigned char)((u >> (8 * i)) & 0xFF);
        f[i] = (float)h;
    }
#endif
}

// ===== fused_pre: hist+rank (blocks < nbE4, 4 slices) || prepack (last 192) ==
// R18: 4 slices (halved edge re-read vs 8; cleanly evaluated this time —
// R16 bundled this with the launch-bounds spill regression).
// 16x16x32 B-fragment order:
// F[((ct*4+kc)*64+l)*8+j] = bf16(W[(kc*32+(l>>4)*8+j)*128 + ct*16+(l&15)])

__global__ __launch_bounds__(256) void fused_pre_kernel(
    const int* __restrict__ rows, int* __restrict__ cnt, int* __restrict__ rank,
    int nE, int n, int nbE4,
    const float* __restrict__ W0, const float* __restrict__ W1,
    const float* __restrict__ W2, unsigned short* __restrict__ F)
{
    const int bid = blockIdx.x;
    if (bid < nbE4) {
        const int g  = bid & 3;
        const int lo = (int)(((long long)g * n) >> 2);
        const int hi = (int)(((long long)(g + 1) * n) >> 2);
        const int idx = (bid >> 2) * 1024 + threadIdx.x * 4;
        if (idx + 3 < nE) {
            int4 r4 = *reinterpret_cast<const int4*>(rows + idx);
            int rk[4] = {-1, -1, -1, -1};
            if (r4.x >= lo && r4.x < hi) rk[0] = atomicAdd(&cnt[r4.x], 1);
            if (r4.y >= lo && r4.y < hi) rk[1] = atomicAdd(&cnt[r4.y], 1);
            if (r4.z >= lo && r4.z < hi) rk[2] = atomicAdd(&cnt[r4.z], 1);
            if (r4.w >= lo && r4.w < hi) rk[3] = atomicAdd(&cnt[r4.w], 1);
            #pragma unroll
            for (int j = 0; j < 4; ++j)
                if (rk[j] >= 0) rank[idx + j] = rk[j];
        } else {
            for (int i = 0; i < 4; ++i)
                if (idx + i < nE) {
                    int r = rows[idx + i];
                    if (r >= lo && r < hi) rank[idx + i] = atomicAdd(&cnt[r], 1);
                }
        }
    } else {
        int gidx = (bid - nbE4) * 256 + threadIdx.x;
        if (gidx >= 3 * 32 * 64 * 8) return;
        const int midx = gidx >> 14;
        const int idx  = gidx & 16383;
        const float* W = midx == 0 ? W0 : (midx == 1 ? W1 : W2);
        int j  = idx & 7;
        int l  = (idx >> 3) & 63;
        int kc = (idx >> 9) & 3;
        int ct = idx >> 11;                        // 0..7
        int kk = kc * 32 + (l >> 4) * 8 + j;
        int c  = ct * 16 + (l & 15);
        F[gidx] = f2bf(W[kk * D + c]);
    }
}

// ================= scan: block sums, then write (with inline boff re-scan) ===

__global__ __launch_bounds__(256) void scan_bsum_kernel(
    const int* __restrict__ cnt, int* __restrict__ bsum, int n)
{
    __shared__ int s[256];
    const int t = threadIdx.x;
    const int base = blockIdx.x * 1024 + t * 4;
    int sum = 0;
    if (base + 3 < n) {
        int4 c4 = *reinterpret_cast<const int4*>(cnt + base);
        sum = c4.x + c4.y + c4.z + c4.w;
    } else {
        for (int i = 0; i < 4; ++i) if (base + i < n) sum += cnt[base + i];
    }
    s[t] = sum;
    __syncthreads();
    #pragma unroll
    for (int off = 128; off > 0; off >>= 1) {
        if (t < off) s[t] += s[t + off];
        __syncthreads();
    }
    if (t == 0) bsum[blockIdx.x] = s[0];
}

__global__ __launch_bounds__(256) void scan_write2_kernel(
    const int* __restrict__ cnt, const int* __restrict__ bsum, int nb,
    int* __restrict__ rowptr, int n)
{
    __shared__ int s[256];
    const int t = threadIdx.x;

    s[t] = (t < nb) ? bsum[t] : 0;
    __syncthreads();
    #pragma unroll
    for (int off = 1; off < 256; off <<= 1) {
        int v = (t >= off) ? s[t - off] : 0;
        __syncthreads();
        s[t] += v;
        __syncthreads();
    }
    const int boffv = (blockIdx.x > 0) ? s[blockIdx.x - 1] : 0;  // exclusive
    const int total = s[255];
    if (blockIdx.x == 0 && t == 0) rowptr[n] = total;
    __syncthreads();

    const int base = blockIdx.x * 1024 + t * 4;
    int c[4] = {0, 0, 0, 0};
    if (base + 3 < n) {
        int4 c4 = *reinterpret_cast<const int4*>(cnt + base);
        c[0] = c4.x; c[1] = c4.y; c[2] = c4.z; c[3] = c4.w;
    } else {
        for (int i = 0; i < 4; ++i) if (base + i < n) c[i] = cnt[base + i];
    }
    const int tsum = c[0] + c[1] + c[2] + c[3];
    s[t] = tsum;
    __syncthreads();
    #pragma unroll
    for (int off = 1; off < 256; off <<= 1) {
        int v = (t >= off) ? s[t - off] : 0;
        __syncthreads();
        s[t] += v;
        __syncthreads();
    }
    int run = boffv + s[t] - tsum;
    int w0 = run;
    int w1 = run + c[0];
    int w2 = w1 + c[1];
    int w3 = w2 + c[2];
    if (base + 3 < n) {
        *reinterpret_cast<int4*>(rowptr + base) = make_int4(w0, w1, w2, w3);
    } else {
        int w[4] = {w0, w1, w2, w3};
        for (int i = 0; i < 4; ++i) if (base + i < n) rowptr[base + i] = w[i];
    }
}

// ===== fused_mid: scatter || proj_q || proj_kv — 16x16x32 MFMA (low VGPR) ====

__global__ __launch_bounds__(256) void fused_mid_kernel(
    const int* __restrict__ rows, const int* __restrict__ cols,
    const int* __restrict__ rank, const int* __restrict__ rowptr,
    int* __restrict__ colsorted, int nE, int n, int nbSc,
    const float* __restrict__ Xq, const float* __restrict__ Xm,
    const unsigned short* __restrict__ Fq, const float* __restrict__ bq,
    unsigned short* __restrict__ qout,
    const unsigned short* __restrict__ Fk, const float* __restrict__ bk,
    const unsigned short* __restrict__ Fv, const float* __restrict__ bv,
    unsigned char* __restrict__ kv, int m, int nTq, int nTm, int nbP)
{
    __shared__ __align__(16) unsigned short sX[2][32][136];
    const int bid = blockIdx.x;
    const int tid = threadIdx.x;

    if (bid < nbSc) {
        // ---- scatter: rank-based, atomic-free, 4 slices ----
        const int g  = bid & 3;
        const int lo = (int)(((long long)g * n) >> 2);
        const int hi = (int)(((long long)(g + 1) * n) >> 2);
        const int idx = (bid >> 2) * 2048 + tid * 8;
        if (idx + 7 < nE) {
            int4 ra = *reinterpret_cast<const int4*>(rows + idx);
            int4 rb = *reinterpret_cast<const int4*>(rows + idx + 4);
            int4 ca = *reinterpret_cast<const int4*>(cols + idx);
            int4 cb = *reinterpret_cast<const int4*>(cols + idx + 4);
            int4 ka = *reinterpret_cast<const int4*>(rank + idx);
            int4 kb = *reinterpret_cast<const int4*>(rank + idx + 4);
            int r[8] = {ra.x, ra.y, ra.z, ra.w, rb.x, rb.y, rb.z, rb.w};
            int c[8] = {ca.x, ca.y, ca.z, ca.w, cb.x, cb.y, cb.z, cb.w};
            int k[8] = {ka.x, ka.y, ka.z, ka.w, kb.x, kb.y, kb.z, kb.w};
            int p[8];
            #pragma unroll
            for (int j = 0; j < 8; ++j)
                p[j] = (r[j] >= lo && r[j] < hi) ? rowptr[r[j]] + k[j] : -1;
            #pragma unroll
            for (int j = 0; j < 8; ++j)
                if (p[j] >= 0) colsorted[p[j]] = c[j];
        } else {
            for (int i = 0; i < 8; ++i)
                if (idx + i < nE) {
                    int r = rows[idx + i];
                    if (r >= lo && r < hi)
                        colsorted[rowptr[r] + rank[idx + i]] = cols[idx + i];
                }
        }
        return;
    }

    // ---- projections: persistent, double-buffered 32-row tiles ----
    const int pb  = bid - nbSc;
    const bool isQ = pb < nbP;
    const float* X = isQ ? Xq : Xm;
    const int nn   = isQ ? n : m;
    const int nT   = isQ ? nTq : nTm;
    int tile       = isQ ? pb : pb - nbP;
    if (tile >= nT) return;

    const int l = tid & 63;
    const int w = tid >> 6;            // wave w owns col-tiles w*2, w*2+1
    const int lr = l & 15;             // A row within 16-row tile; also C col
    const int lg = l >> 4;             // k-group (A/B) and row-group (C/D)
    const int col0 = (w * 2)     * 16 + lr;
    const int col1 = (w * 2 + 1) * 16 + lr;

    float4 r4[4];
    auto LOAD = [&](int t) {
        const int row0 = t * 32;
        #pragma unroll
        for (int p = 0; p < 4; ++p) {
            int flat = p * 256 + tid;
            int rr = flat >> 5;
            int cc = (flat & 31) * 4;
            int gr = row0 + rr; if (gr >= nn) gr = nn - 1;
            r4[p] = *reinterpret_cast<const float4*>(X + (size_t)gr * D + cc);
        }
    };
    auto STORE_LDS = [&](int buf) {
        #pragma unroll
        for (int p = 0; p < 4; ++p) {
            int flat = p * 256 + tid;
            int rr = flat >> 5;
            int cc = (flat & 31) * 4;
            uint2 pk;
            pk.x = (unsigned)f2bf(r4[p].x) | ((unsigned)f2bf(r4[p].y) << 16);
            pk.y = (unsigned)f2bf(r4[p].z) | ((unsigned)f2bf(r4[p].w) << 16);
            *reinterpret_cast<uint2*>(&sX[buf][rr][cc]) = pk;
        }
    };

    LOAD(tile);
    STORE_LDS(0);
    int cur = 0;

    const float bq0 = isQ ? bq[col0] : bk[col0];
    const float bq1 = isQ ? bq[col1] : bk[col1];
    const float bv0 = isQ ? 0.0f : bv[col0];
    const float bv1 = isQ ? 0.0f : bv[col1];

    while (tile < nT) {
        const int next = tile + nbP;
        __syncthreads();                       // sX[cur] ready; cross-buffer hazards fenced
        if (next < nT) LOAD(next);             // in flight during compute

        const int row0 = tile * 32;

        #pragma unroll 1
        for (int rt = 0; rt < 2; ++rt) {       // 16-row sub-tiles
            const int rbase = row0 + rt * 16 + lg * 4;
            if (isQ) {
                #pragma unroll 1
                for (int ci = 0; ci < 2; ++ci) {
                    const int ct = w * 2 + ci;
                    f32x4 acc = {};
                    #pragma unroll
                    for (int kc = 0; kc < 4; ++kc) {
                        bf16x8 af = *reinterpret_cast<const bf16x8*>(
                            &sX[cur][rt * 16 + lr][kc * 32 + lg * 8]);
                        bf16x8 bf = *reinterpret_cast<const bf16x8*>(
                            Fq + ((size_t)((ct * 4 + kc) * 64 + l) * 8));
                        acc = __builtin_amdgcn_mfma_f32_16x16x32_bf16(af, bf, acc, 0, 0, 0);
                    }
                    const int col = ci ? col1 : col0;
                    const float bb = ci ? bq1 : bq0;
                    #pragma unroll
                    for (int reg = 0; reg < 4; ++reg) {
                        int gr = rbase + reg;
                        if (gr < nn)
                            qout[(size_t)gr * D + col] = f2bf(gelu_fast(acc[reg] + bb));
                    }
                }
            } else {
                #pragma unroll 1
                for (int mat = 0; mat < 2; ++mat) {
                    const unsigned short* F = mat ? Fv : Fk;
                    #pragma unroll 1
                    for (int ci = 0; ci < 2; ++ci) {
                        const int ct = w * 2 + ci;
                        f32x4 acc = {};
                        #pragma unroll
                        for (int kc = 0; kc < 4; ++kc) {
                            bf16x8 af = *reinterpret_cast<const bf16x8*>(
                                &sX[cur][rt * 16 + lr][kc * 32 + lg * 8]);
                            bf16x8 bf = *reinterpret_cast<const bf16x8*>(
                                F + ((size_t)((ct * 4 + kc) * 64 + l) * 8));
                            acc = __builtin_amdgcn_mfma_f32_16x16x32_bf16(af, bf, acc, 0, 0, 0);
                        }
                        const int col = ci ? col1 : col0;
                        const float bb = mat ? (ci ? bv1 : bv0) : (ci ? bq1 : bq0);
                        #pragma unroll
                        for (int reg = 0; reg < 4; ++reg) {
                            int gr = rbase + reg;
                            if (gr < nn) {
                                unsigned char* rec = kv + (size_t)gr * KVREC;
                                float val = gelu_fast(acc[reg] + bb);
                                if (mat == 0)
                                    rec[col] = f2fp8(val);
                                else
                                    reinterpret_cast<unsigned short*>(rec + 128)[col] = f2bf(val);
                            }
                        }
                    }
                }
            }
        }

        if (next < nT) STORE_LDS(cur ^ 1);     // waits on LOAD(next) only here
        cur ^= 1;
        tile = next;
    }
}

// ===== aggregation: one wave/row, 4 edge slots x 16 dim lanes ================
// R18: colsorted prefetched 4 iterations ahead + unroll 4 -> up to 16
// outstanding kv gathers per wave.
__global__ __launch_bounds__(256) void agg_kernel(
    const unsigned short* __restrict__ q, const unsigned char* __restrict__ kv,
    const int* __restrict__ rowptr, const int* __restrict__ colsorted,
    float* __restrict__ out, int n)
{
    const int wave = (blockIdx.x * 256 + threadIdx.x) >> 6;
    if (wave >= n) return;
    const int lane = threadIdx.x & 63;
    const int sub  = lane >> 4;
    const int l    = lane & 15;

    const uint4 qa = *reinterpret_cast<const uint4*>(q + (size_t)wave * D + l * 8);
    float qf[8];
    qf[0] = bflo(qa.x); qf[1] = bfhi(qa.x);
    qf[2] = bflo(qa.y); qf[3] = bfhi(qa.y);
    qf[4] = bflo(qa.z); qf[5] = bfhi(qa.z);
    qf[6] = bflo(qa.w); qf[7] = bfhi(qa.w);

    float acc[8] = {0.f,0.f,0.f,0.f,0.f,0.f,0.f,0.f};
    const int start = rowptr[wave], end = rowptr[wave + 1];

    int i  = start + sub;
    int cA = (i      < end) ? colsorted[i]      : 0;
    int cB = (i + 4  < end) ? colsorted[i + 4]  : 0;
    int cC = (i + 8  < end) ? colsorted[i + 8]  : 0;
    int cD = (i + 12 < end) ? colsorted[i + 12] : 0;

    #pragma unroll 4
    for (; i < end; i += 4) {
        const int c = cA;
        cA = cB; cB = cC; cC = cD;
        cD = (i + 16 < end) ? colsorted[i + 16] : 0;

        const unsigned char* rec = kv + (size_t)c * KVREC;
        const uint2 kb = *reinterpret_cast<const uint2*>(rec + l * 8);
        const uint4 vb = *reinterpret_cast<const uint4*>(rec + 128 + l * 16);

        float kf[8];
        fp8x4d(kb.x, kf); fp8x4d(kb.y, kf + 4);

        float dot = 0.0f;
        #pragma unroll
        for (int j = 0; j < 8; ++j) dot = fmaf(qf[j], kf[j], dot);
        dot += __shfl_xor(dot, 1);
        dot += __shfl_xor(dot, 2);
        dot += __shfl_xor(dot, 4);
        dot += __shfl_xor(dot, 8);
        const float coef = 1.0f / (1.0f + __expf(-dot * 0.08838834764831845f));

        acc[0] = fmaf(coef, bflo(vb.x), acc[0]);
        acc[1] = fmaf(coef, bfhi(vb.x), acc[1]);
        acc[2] = fmaf(coef, bflo(vb.y), acc[2]);
        acc[3] = fmaf(coef, bfhi(vb.y), acc[3]);
        acc[4] = fmaf(coef, bflo(vb.z), acc[4]);
        acc[5] = fmaf(coef, bfhi(vb.z), acc[5]);
        acc[6] = fmaf(coef, bflo(vb.w), acc[6]);
        acc[7] = fmaf(coef, bfhi(vb.w), acc[7]);
    }

    #pragma unroll
    for (int j = 0; j < 8; ++j) {
        acc[j] += __shfl_xor(acc[j], 16);
        acc[j] += __shfl_xor(acc[j], 32);
    }

    if (sub == 0) {
        float* op = out + (size_t)wave * D + l * 8;
        float4 o0 = {acc[0], acc[1], acc[2], acc[3]};
        float4 o1 = {acc[4], acc[5], acc[6], acc[7]};
        *reinterpret_cast<float4*>(op)     = o0;
        *reinterpret_cast<float4*>(op + 4) = o1;
    }
}

extern "C" void kernel_launch(void* const* d_in, const int* in_sizes, int n_in,
                              void* d_out, int out_size, void* d_ws, size_t ws_size,
                              hipStream_t stream) {
    const float* query  = (const float*)d_in[0];
    const float* memory = (const float*)d_in[1];
    const float* Wq     = (const float*)d_in[2];
    const float* bq     = (const float*)d_in[3];
    const float* Wk     = (const float*)d_in[4];
    const float* bk     = (const float*)d_in[5];
    const float* Wv     = (const float*)d_in[6];
    const float* bv     = (const float*)d_in[7];
    const int*   erows  = (const int*)d_in[8];
    const int*   ecols  = (const int*)d_in[9];

    const int n  = in_sizes[0] / D;   // 100000
    const int m  = in_sizes[1] / D;   // 100000
    const int nE = in_sizes[8];       // 1600000

    char* base = (char*)d_ws;
    size_t off = 0;
    auto carve = [&](size_t bytes) -> char* {
        char* p = base + off;
        off = (off + bytes + 255) & ~(size_t)255;
        return p;
    };
    unsigned short* q   = (unsigned short*)carve((size_t)n * D * sizeof(unsigned short));
    unsigned char*  kv  = (unsigned char*) carve((size_t)m * KVREC);
    unsigned short* F   = (unsigned short*)carve(3 * 32 * 64 * 8 * sizeof(unsigned short));
    int*   rowptr    = (int*)carve((size_t)(n + 1) * sizeof(int));
    int*   cnt       = (int*)carve((size_t)(n + 1) * sizeof(int));
    int*   rank      = (int*)carve((size_t)nE * sizeof(int));
    int*   bsum      = (int*)carve(256 * sizeof(int));
    int*   colsorted = (int*)carve((size_t)nE * sizeof(int));
    float* out       = (float*)d_out;

    unsigned short* Fq = F;
    unsigned short* Fk = F + 16384;
    unsigned short* Fv = F + 32768;

    dim3 blk(256);
    const int nbScan = (n + 1023) / 1024;            // 98 <= 256
    const int nbE4   = ((nE + 1023) / 1024) * 4;     // hist blocks (4 edges/thr, 4 slices)
    const int nbSc   = ((nE + 2047) / 2048) * 4;     // scatter blocks (8 edges/thr, 4 slices)
    const int nTq    = (n + 31) / 32;                // 32-row proj tiles
    const int nTm    = (m + 31) / 32;
    const int nbP    = 1024;                         // persistent proj blocks per matrix

    // 1) zero counters
    hipMemsetAsync(cnt, 0, (size_t)(n + 1) * sizeof(int), stream);
    // 2) hist(+rank) || prepack (16x16x32 fragment order)
    fused_pre_kernel<<<dim3(nbE4 + 192), blk, 0, stream>>>(
        erows, cnt, rank, nE, n, nbE4, Wq, Wk, Wv, F);
    // 3) block sums
    scan_bsum_kernel<<<dim3(nbScan), blk, 0, stream>>>(cnt, bsum, n);
    // 4) rowptr (inline boff re-scan)
    scan_write2_kernel<<<dim3(nbScan), blk, 0, stream>>>(cnt, bsum, nbScan, rowptr, n);
    // 5) scatter || proj_q || proj_kv (16x16 MFMA, natural VGPR allocation)
    fused_mid_kernel<<<dim3(nbSc + 2 * nbP), blk, 0, stream>>>(
        erows, ecols, rank, rowptr, colsorted, nE, n, nbSc,
        query, memory, Fq, bq, q, Fk, bk, Fv, bv, kv, m, nTq, nTm, nbP);
    // 6) aggregation (writes all outputs; no out memset needed)
    agg_kernel<<<dim3((n * 64 + 255) / 256), blk, 0, stream>>>(q, kv, rowptr, colsorted, out, n);
}